// Round 6
// baseline (418.208 us; speedup 1.0000x reference)
//
#include <hip/hip_runtime.h>
#include <stdint.h>

#define NB 32
#define SEQ 577
#define SPAD 640
#define NH 16
#define HD 64
#define DM 1024
#define MTOT (NB * SEQ) /* 18464 */
#define KT_N 16         /* K-tiles of 64: 1024/64 */

typedef __bf16 bf16x8 __attribute__((ext_vector_type(8)));
typedef float f32x4 __attribute__((ext_vector_type(4)));
typedef unsigned short u16x8 __attribute__((ext_vector_type(8)));
typedef unsigned short u16x4 __attribute__((ext_vector_type(4)));

__device__ __forceinline__ unsigned short f2bf(float f) {
  unsigned int u = __builtin_bit_cast(unsigned int, f);
  return (unsigned short)((u + 0x7FFFu + ((u >> 16) & 1u)) >> 16);
}

__device__ __forceinline__ f32x4 mfma16(bf16x8 a, bf16x8 b, f32x4 c) {
  return __builtin_amdgcn_mfma_f32_16x16x32_bf16(a, b, c, 0, 0, 0);
}

__device__ __forceinline__ void gload16(const unsigned short* g, unsigned short* l) {
  __builtin_amdgcn_global_load_lds(
      (const __attribute__((address_space(1))) unsigned int*)g,
      (__attribute__((address_space(3))) unsigned int*)l, 16, 0, 0);
}

#define BC8(p) __builtin_bit_cast(bf16x8, *(const u16x8*)(p))

#if __has_builtin(__builtin_amdgcn_exp2f)
#define EXP2(x) __builtin_amdgcn_exp2f(x)
#else
#define EXP2(x) exp2f(x)
#endif

// ---------------- fp32 -> bf16 conversion of x and the 3 weight matrices ----
__global__ void cvt_kernel(const float* __restrict__ x,
                           const float* __restrict__ wq,
                           const float* __restrict__ wk,
                           const float* __restrict__ wv,
                           unsigned short* __restrict__ xb,
                           unsigned short* __restrict__ wb) {
  const long long NX = (long long)MTOT * DM;
  long long i = ((long long)blockIdx.x * blockDim.x + threadIdx.x) * 4;
  const float* src;
  unsigned short* dst;
  if (i < NX) {
    src = x + i;
    dst = xb + i;
  } else {
    long long j = i - NX;                 // 0 .. 3*2^20-1, DM*DM = 2^20
    int wsel = (int)(j >> 20);
    long long off = j & 0xFFFFF;
    src = (wsel == 0 ? wq : wsel == 1 ? wk : wv) + off;
    dst = wb + j;
  }
  f32x4 v = *(const f32x4*)src;
  u16x4 o;
  o.x = f2bf(v.x); o.y = f2bf(v.y); o.z = f2bf(v.z); o.w = f2bf(v.w);
  *(u16x4*)dst = o;
}

// ---------------- 256^2 BK=64 GEMM, 4-barrier pipelined schedule ------------
// R3: one barrier per phase. Phase = {stage-issue (disjoint region);
// ds_reads; lgkmcnt(0); setprio1 16xMFMA setprio0; BARRIER}.
// Hazard proof: region R staged in phase p+1 was read ONLY in phase <= p;
// each wave's reads complete at its own lgkmcnt(0) (pre-MFMA), so the
// phase-p BARRIER guarantees all waves' reads of R are done before any
// wave issues p+1's stage into R. Within a phase, stage and read regions
// are disjoint by construction. vmcnt(8) once per K-tile (never 0):
// kt+2 staged during kt; at iteration end >=8 in flight = kt+2's only,
// so kt+1's data is resident before the next iteration reads it.
// MODE 0: Q/K (normal orientation). MODE 1: V (operand-swapped -> C^T,
// epilogue stores coalesced along s).
template <int MODE>
__global__ __launch_bounds__(512, 2) void gemm256(
    const unsigned short* __restrict__ xb, const unsigned short* __restrict__ wb,
    const float* __restrict__ bq, const float* __restrict__ bk,
    const float* __restrict__ bv,
    unsigned short* __restrict__ qo, unsigned short* __restrict__ ko,
    unsigned short* __restrict__ vo) {
  __shared__ __align__(16) unsigned short LDS[65536];  // 128 KiB
  const int id = blockIdx.x;
  int m_tile, col, z;
  if constexpr (MODE == 0) {
    // 584 blocks: m-major per XCD (p = xcd*73 + j), 8 cols per m-tile
    const int xcd = id & 7, j = id >> 3;
    const int p = xcd * 73 + j;       // bijective, 0..583
    m_tile = p >> 3;                  // 0..72
    col = p & 7;                      // 0..7
    z = col >> 2;                     // 0: Q, 1: K
  } else {
    // 292 blocks: bijective chunked remap (292 = 8*36 + 4)
    const int xcd = id & 7, j = id >> 3;
    const int p = (xcd < 4) ? xcd * 37 + j : 148 + (xcd - 4) * 36 + j;
    m_tile = p >> 2;                  // 0..72
    col = p & 3;                      // 0..3
    z = 2;
  }
  const int n0 = (MODE == 0 ? (col & 3) : col) * 256;
  const int m0 = m_tile * 256;

  const int t = threadIdx.x;        // 0..511
  const int lane = t & 63;
  const int w = t >> 6;             // 8 waves
  const int g = lane >> 4, c = lane & 15;
  const int wm = w & 1, wn = w >> 1;

  const unsigned short* W = wb + (size_t)z * (DM * DM);
  const float* bias = (MODE == 1) ? bv : (z ? bk : bq);
  unsigned short* outp = (MODE == 1) ? vo : (z ? ko : qo);

  const int srow = t >> 3;
  const int schunk = (t & 7) ^ (srow & 7);
  const unsigned short* gA[4];
#pragma unroll
  for (int q = 0; q < 4; q++) {
    int rg = m0 + q * 64 + srow;
    if (rg > MTOT - 1) rg = MTOT - 1;
    gA[q] = xb + (size_t)rg * DM + schunk * 8;
  }
  const unsigned short* gB[4];
#pragma unroll
  for (int q = 0; q < 4; q++)
    gB[q] = W + (size_t)(n0 + q * 64 + srow) * DM + schunk * 8;

  const int cx = c & 7;
  const int ch0 = (g ^ cx) * 8;        // kk=0 (k 0..31)
  const int ch1 = ((4 + g) ^ cx) * 8;  // kk=1 (k 32..63)

  f32x4 acc[8][4];
#pragma unroll
  for (int mi = 0; mi < 8; mi++)
#pragma unroll
    for (int ni = 0; ni < 4; ni++) acc[mi][ni] = (f32x4)0.0f;

  // prologue: stage K-tile 0 -> buf0, K-tile 1 -> buf1 (16 issues), wait 8
#pragma unroll
  for (int q = 0; q < 4; q++) gload16(gA[q], LDS + q * 4096 + t * 8);
#pragma unroll
  for (int q = 0; q < 4; q++) gload16(gB[q], LDS + 16384 + q * 4096 + t * 8);
#pragma unroll
  for (int q = 0; q < 4; q++) gload16(gA[q] + 64, LDS + 32768 + q * 4096 + t * 8);
#pragma unroll
  for (int q = 0; q < 4; q++)
    gload16(gB[q] + 64, LDS + 32768 + 16384 + q * 4096 + t * 8);
  asm volatile("s_waitcnt vmcnt(8)" ::: "memory");
  __builtin_amdgcn_sched_barrier(0);
  __builtin_amdgcn_s_barrier();

  const int rA0 = wm * 128 + c;
  const int rB0 = wn * 64 + c;

#define MM(ACC, AF, BF)                                   \
  do {                                                    \
    if constexpr (MODE == 0)                              \
      ACC = mfma16(AF, BF, ACC);                          \
    else                                                  \
      ACC = mfma16(BF, AF, ACC);                          \
  } while (0)

  for (int kt = 0; kt < KT_N; ++kt) {
    unsigned short* ab = LDS + (kt & 1) * 32768;
    unsigned short* bb = ab + 16384;
    const bool st = (kt + 2) < KT_N;
    const int ko2 = (kt + 2) * 64;
    bf16x8 af[4][2], bf0[2][2], bf1[2][2];

    // -- phase 0: reads A-lo + B01; MFMA lo x ni01; barrier
#pragma unroll
    for (int mi = 0; mi < 4; mi++) {
      const unsigned short* rp = ab + (rA0 + mi * 16) * 64;
      af[mi][0] = BC8(rp + ch0);
      af[mi][1] = BC8(rp + ch1);
    }
#pragma unroll
    for (int ni = 0; ni < 2; ni++) {
      const unsigned short* rp = bb + (rB0 + ni * 16) * 64;
      bf0[ni][0] = BC8(rp + ch0);
      bf0[ni][1] = BC8(rp + ch1);
    }
    asm volatile("s_waitcnt lgkmcnt(0)" ::: "memory");
    __builtin_amdgcn_sched_barrier(0);
    __builtin_amdgcn_s_setprio(1);
#pragma unroll
    for (int mi = 0; mi < 4; mi++)
#pragma unroll
      for (int ni = 0; ni < 2; ni++) {
        MM(acc[mi][ni], af[mi][0], bf0[ni][0]);
        MM(acc[mi][ni], af[mi][1], bf0[ni][1]);
      }
    __builtin_amdgcn_s_setprio(0);
    __builtin_amdgcn_s_barrier();

    // -- phase 1: stage A q0,q2 (read in p0); reads B23; MFMA lo x ni23
    if (st) {
      gload16(gA[0] + ko2, ab + 0 * 4096 + t * 8);
      gload16(gA[2] + ko2, ab + 2 * 4096 + t * 8);
    }
#pragma unroll
    for (int ni = 0; ni < 2; ni++) {
      const unsigned short* rp = bb + (rB0 + (2 + ni) * 16) * 64;
      bf1[ni][0] = BC8(rp + ch0);
      bf1[ni][1] = BC8(rp + ch1);
    }
    asm volatile("s_waitcnt lgkmcnt(0)" ::: "memory");
    __builtin_amdgcn_sched_barrier(0);
    __builtin_amdgcn_s_setprio(1);
#pragma unroll
    for (int mi = 0; mi < 4; mi++)
#pragma unroll
      for (int ni = 0; ni < 2; ni++) {
        MM(acc[mi][2 + ni], af[mi][0], bf1[ni][0]);
        MM(acc[mi][2 + ni], af[mi][1], bf1[ni][1]);
      }
    __builtin_amdgcn_s_setprio(0);
    __builtin_amdgcn_s_barrier();

    // -- phase 2: stage B all (read in p0/p1); reads A-hi; MFMA hi x ni23
    if (st) {
#pragma unroll
      for (int q = 0; q < 4; q++) gload16(gB[q] + ko2, bb + q * 4096 + t * 8);
    }
#pragma unroll
    for (int mi = 0; mi < 4; mi++) {
      const unsigned short* rp = ab + (rA0 + 64 + mi * 16) * 64;
      af[mi][0] = BC8(rp + ch0);
      af[mi][1] = BC8(rp + ch1);
    }
    asm volatile("s_waitcnt lgkmcnt(0)" ::: "memory");
    __builtin_amdgcn_sched_barrier(0);
    __builtin_amdgcn_s_setprio(1);
#pragma unroll
    for (int mi = 0; mi < 4; mi++)
#pragma unroll
      for (int ni = 0; ni < 2; ni++) {
        MM(acc[4 + mi][2 + ni], af[mi][0], bf1[ni][0]);
        MM(acc[4 + mi][2 + ni], af[mi][1], bf1[ni][1]);
      }
    __builtin_amdgcn_s_setprio(0);
    __builtin_amdgcn_s_barrier();

    // -- phase 3: stage A q1,q3 (read in p2); MFMA hi x ni01; vmcnt(8)
    if (st) {
      gload16(gA[1] + ko2, ab + 1 * 4096 + t * 8);
      gload16(gA[3] + ko2, ab + 3 * 4096 + t * 8);
    }
    __builtin_amdgcn_s_setprio(1);
#pragma unroll
    for (int mi = 0; mi < 4; mi++)
#pragma unroll
      for (int ni = 0; ni < 2; ni++) {
        MM(acc[4 + mi][ni], af[mi][0], bf0[ni][0]);
        MM(acc[4 + mi][ni], af[mi][1], bf0[ni][1]);
      }
    __builtin_amdgcn_s_setprio(0);
    asm volatile("s_waitcnt vmcnt(8)" ::: "memory");
    __builtin_amdgcn_sched_barrier(0);
    __builtin_amdgcn_s_barrier();
  }
#undef MM

  if constexpr (MODE == 0) {
    float bias4[4];
#pragma unroll
    for (int ni = 0; ni < 4; ni++) bias4[ni] = bias[n0 + wn * 64 + ni * 16 + c];
#pragma unroll
    for (int mi = 0; mi < 8; mi++) {
      int mb = m0 + wm * 128 + mi * 16 + g * 4;
#pragma unroll
      for (int r = 0; r < 4; r++) {
        int m = mb + r;
        if (m >= MTOT) continue;
        int bi = m / SEQ;
        int s = m - bi * SEQ;
#pragma unroll
        for (int ni = 0; ni < 4; ni++) {
          int n = n0 + wn * 64 + ni * 16 + c;
          int hh = n >> 6, dd = n & 63;
          outp[(((size_t)bi * NH + hh) * SPAD + s) * HD + dd] =
              f2bf(acc[mi][ni][r] + bias4[ni]);
        }
      }
    }
  } else {
    // C^T: acc[mi][ni] elem (r, lane c): n = n0+wn*64+ni*16+g*4+r,
    // m = m0+wm*128+mi*16+c. Lanes c -> consecutive s (coalesced).
#pragma unroll
    for (int ni = 0; ni < 4; ni++) {
#pragma unroll
      for (int r = 0; r < 4; r++) {
        int n = n0 + wn * 64 + ni * 16 + g * 4 + r;
        int hh = n >> 6, dd = n & 63;
        float bn = bias[n];
#pragma unroll
        for (int mi = 0; mi < 8; mi++) {
          int m = m0 + wm * 128 + mi * 16 + c;
          if (m >= MTOT) continue;
          int bi = m / SEQ;
          int s = m - bi * SEQ;
          outp[(((size_t)bi * NH + hh) * HD + dd) * SPAD + s] =
              f2bf(acc[mi][ni][r] + bn);
        }
      }
    }
  }
}

// ---------------- flash attention v2 (R0: XCD-locality remap, kept) ---------
__global__ __launch_bounds__(256, 4) void attn_kernel(
    const unsigned short* __restrict__ Qb, const unsigned short* __restrict__ Kb,
    const unsigned short* __restrict__ Vt, float* __restrict__ out) {
  __shared__ __align__(16) unsigned short Ks[64 * 64];
  __shared__ __align__(16) unsigned short Vs[80 * 64];
  __shared__ __align__(16) unsigned short Pl[4][16 * 72];
  const int t = threadIdx.x, lane = t & 63, w = t >> 6;
  const int g = lane >> 4, c = lane & 15;

  const int id = blockIdx.x;          // 0..5119
  const int xcd = id & 7;
  const int slot = id >> 3;           // 0..639
  const int qt = slot % 10;
  const int pairIdx = slot / 10;      // 0..63
  const int pair = xcd * 64 + pairIdx;
  const int b = pair >> 4;
  const int h = pair & 15;

  const int q0 = qt * 64 + w * 16;
  const size_t bh = (size_t)b * NH + h;
  const unsigned short* Qp = Qb + bh * SPAD * HD;
  const unsigned short* Kp = Kb + bh * SPAD * HD;
  const unsigned short* Vp = Vt + bh * HD * SPAD;

  {
    int rr = t >> 4, col = (t & 15) * 4;
    unsigned short val = (rr == 0) ? (unsigned short)0x3F80 : (unsigned short)0;
    u16x4 v4 = {val, val, val, val};
    *(u16x4*)(Vs + (64 + rr) * 64 + col) = v4;
  }

  bf16x8 qf0 = __builtin_bit_cast(
      bf16x8, *(const u16x8*)(Qp + (size_t)(q0 + c) * HD + g * 8));
  bf16x8 qf1 = __builtin_bit_cast(
      bf16x8, *(const u16x8*)(Qp + (size_t)(q0 + c) * HD + 32 + g * 8));

  const int C0 = t, C1 = t + 256;
  const int r0 = C0 >> 3, cg0 = (C0 & 7) ^ (r0 & 7);
  const int r1 = C1 >> 3, cg1 = (C1 & 7) ^ (r1 & 7);
  const unsigned short* gK0 = Kp + (size_t)(r0 * 8 + cg0) * 8;
  const unsigned short* gK1 = Kp + (size_t)(r1 * 8 + cg1) * 8;
  const unsigned short* gV0 = Vp + (size_t)r0 * SPAD + cg0 * 8;
  const unsigned short* gV1 = Vp + (size_t)r1 * SPAD + cg1 * 8;
  unsigned short* lK0 = Ks + C0 * 8;
  unsigned short* lK1 = Ks + C1 * 8;
  unsigned short* lV0 = Vs + C0 * 8;
  unsigned short* lV1 = Vs + C1 * 8;

  f32x4 oacc[5];
#pragma unroll
  for (int nt = 0; nt < 5; nt++) oacc[nt] = (f32x4)0.0f;
  unsigned short* pl = &Pl[w][0];
  const float SC = 0.125f * 1.44269504f;

  for (int kt = 0; kt < 10; kt++) {
    const int kv0 = kt * 64;
    __syncthreads();
    gload16(gK0 + kv0 * 64, lK0);
    gload16(gK1 + kv0 * 64, lK1);
    gload16(gV0 + kv0, lV0);
    gload16(gV1 + kv0, lV1);
    __syncthreads();

    f32x4 sc[4];
#pragma unroll
    for (int nt = 0; nt < 4; nt++) {
      const int row = nt * 16 + c;
      const unsigned short* kb = Ks + row * 64;
      bf16x8 k0 = __builtin_bit_cast(
          bf16x8, *(const u16x8*)(kb + ((g ^ (row & 7)) * 8)));
      bf16x8 k1 = __builtin_bit_cast(
          bf16x8, *(const u16x8*)(kb + (((4 + g) ^ (row & 7)) * 8)));
      sc[nt] = mfma16(qf0, k0, (f32x4)0.0f);
      sc[nt] = mfma16(qf1, k1, sc[nt]);
    }

    if (kt == 9) {
#pragma unroll
      for (int nt = 0; nt < 4; nt++) {
        const bool valid = (kv0 + nt * 16 + c) < SEQ;
#pragma unroll
        for (int r = 0; r < 4; r++)
          sc[nt][r] = valid ? EXP2(sc[nt][r] * SC) : 0.0f;
      }
    } else {
#pragma unroll
      for (int nt = 0; nt < 4; nt++)
#pragma unroll
        for (int r = 0; r < 4; r++) sc[nt][r] = EXP2(sc[nt][r] * SC);
    }

#pragma unroll
    for (int nt = 0; nt < 4; nt++)
#pragma unroll
      for (int r = 0; r < 4; r++)
        pl[(g * 4 + r) * 72 + nt * 16 + c] = f2bf(sc[nt][r]);
    bf16x8 pa0 = __builtin_bit_cast(bf16x8, *(const u16x8*)(pl + c * 72 + g * 8));
    bf16x8 pa1 =
        __builtin_bit_cast(bf16x8, *(const u16x8*)(pl + c * 72 + 32 + g * 8));

#pragma unroll
    for (int nt = 0; nt < 5; nt++) {
      const int row = nt * 16 + c;
      const unsigned short* vb = Vs + row * 64;
      bf16x8 v0 = __builtin_bit_cast(
          bf16x8, *(const u16x8*)(vb + ((g ^ (row & 7)) * 8)));
      bf16x8 v1 = __builtin_bit_cast(
          bf16x8, *(const u16x8*)(vb + (((4 + g) ^ (row & 7)) * 8)));
      oacc[nt] = mfma16(pa0, v0, oacc[nt]);
      oacc[nt] = mfma16(pa1, v1, oacc[nt]);
    }
  }

#pragma unroll
  for (int r = 0; r < 4; r++) {
    int s = q0 + g * 4 + r;
    if (s >= SEQ) continue;
    float l = __shfl(oacc[4][r], lane & 48, 64);
    float inv = 1.0f / l;
#pragma unroll
    for (int nt = 0; nt < 4; nt++)
      out[((size_t)b * SEQ + s) * DM + h * HD + nt * 16 + c] =
          oacc[nt][r] * inv;
  }
}

extern "C" void kernel_launch(void* const* d_in, const int* in_sizes, int n_in,
                              void* d_out, int out_size, void* d_ws,
                              size_t ws_size, hipStream_t stream) {
  const float* x = (const float*)d_in[0];
  const float* Wq = (const float*)d_in[1];
  const float* bq = (const float*)d_in[2];
  const float* Wk = (const float*)d_in[3];
  const float* bk = (const float*)d_in[4];
  const float* Wv = (const float*)d_in[5];
  const float* bv = (const float*)d_in[6];
  float* out = (float*)d_out;

  const size_t nXB = (size_t)MTOT * DM;
  const size_t nWB = (size_t)3 * DM * DM;
  const size_t nQK = (size_t)NB * NH * SPAD * HD;
  const size_t needed = (nXB + nWB + 3 * nQK) * 2;
  if (ws_size < needed) return;

  unsigned short* xb = (unsigned short*)d_ws;
  unsigned short* wb = xb + nXB;
  unsigned short* Qb = wb + nWB;
  unsigned short* Kb = Qb + nQK;
  unsigned short* Vt = Kb + nQK;

  cvt_kernel<<<21536, 256, 0, stream>>>(x, Wq, Wk, Wv, xb, wb);
  gemm256<0><<<584, 512, 0, stream>>>(xb, wb, bq, bk, bv, Qb, Kb, Vt);
  gemm256<1><<<292, 512, 0, stream>>>(xb, wb, bq, bk, bv, Qb, Kb, Vt);
  attn_kernel<<<5120, 256, 0, stream>>>(Qb, Kb, Vt, out);
}

// Round 7
// 385.665 us; speedup vs baseline: 1.0844x; 1.0844x over previous
//
#include <hip/hip_runtime.h>
#include <stdint.h>

#define NB 32
#define SEQ 577
#define SPAD 640
#define NH 16
#define HD 64
#define DM 1024
#define MTOT (NB * SEQ) /* 18464 */
#define KT_N 16         /* K-tiles of 64: 1024/64 */

typedef __bf16 bf16x8 __attribute__((ext_vector_type(8)));
typedef float f32x4 __attribute__((ext_vector_type(4)));
typedef unsigned short u16x8 __attribute__((ext_vector_type(8)));
typedef unsigned short u16x4 __attribute__((ext_vector_type(4)));

__device__ __forceinline__ unsigned short f2bf(float f) {
  unsigned int u = __builtin_bit_cast(unsigned int, f);
  return (unsigned short)((u + 0x7FFFu + ((u >> 16) & 1u)) >> 16);
}

__device__ __forceinline__ f32x4 mfma16(bf16x8 a, bf16x8 b, f32x4 c) {
  return __builtin_amdgcn_mfma_f32_16x16x32_bf16(a, b, c, 0, 0, 0);
}

__device__ __forceinline__ void gload16(const unsigned short* g, unsigned short* l) {
  __builtin_amdgcn_global_load_lds(
      (const __attribute__((address_space(1))) unsigned int*)g,
      (__attribute__((address_space(3))) unsigned int*)l, 16, 0, 0);
}

#define BC8(p) __builtin_bit_cast(bf16x8, *(const u16x8*)(p))

#if __has_builtin(__builtin_amdgcn_exp2f)
#define EXP2(x) __builtin_amdgcn_exp2f(x)
#else
#define EXP2(x) exp2f(x)
#endif

// ---------------- fp32 -> bf16 conversion of x and the 3 weight matrices ----
__global__ void cvt_kernel(const float* __restrict__ x,
                           const float* __restrict__ wq,
                           const float* __restrict__ wk,
                           const float* __restrict__ wv,
                           unsigned short* __restrict__ xb,
                           unsigned short* __restrict__ wb) {
  const long long NX = (long long)MTOT * DM;
  long long i = ((long long)blockIdx.x * blockDim.x + threadIdx.x) * 4;
  const float* src;
  unsigned short* dst;
  if (i < NX) {
    src = x + i;
    dst = xb + i;
  } else {
    long long j = i - NX;                 // 0 .. 3*2^20-1, DM*DM = 2^20
    int wsel = (int)(j >> 20);
    long long off = j & 0xFFFFF;
    src = (wsel == 0 ? wq : wsel == 1 ? wk : wv) + off;
    dst = wb + j;
  }
  f32x4 v = *(const f32x4*)src;
  u16x4 o;
  o.x = f2bf(v.x); o.y = f2bf(v.y); o.z = f2bf(v.z); o.w = f2bf(v.w);
  *(u16x4*)dst = o;
}

// ---------------- 256^2 BK=64 K-loop, counted-lgkm schedule (R6) -----------
// Phase = {stage-issue; ds_reads; setprio1 MFMA setprio0 (compiler emits
// COUNTED lgkmcnt per consumer -- no forced pre-MFMA drain); lgkmcnt(0)
// [WAR fence, free since reads long done]; s_barrier; sched_barrier(0)
// [pins next phase's stage-issues behind the barrier]}.
// Region safety identical to R3 proof: region staged in phase p+1 was last
// read in phase <= p, whose readers drained at their lgkmcnt(0) before the
// phase-p barrier. vmcnt(8) once per K-tile retires kt+1's loads (16 in
// flight -> 8); kt==KT_N-2 uses vmcnt(0) (fixes latent race: with no new
// issues, vmcnt(8) passed while kt+1's 8 loads were still in flight).
template <int MODE>
__device__ __forceinline__ void kloop256(
    unsigned short* LDS, const unsigned short* const* gA,
    const unsigned short* const* gB, f32x4 (&acc)[8][4],
    int rA0, int rB0, int ch0, int ch1) {
#define MM(ACC, AF, BF)                                   \
  do {                                                    \
    if constexpr (MODE == 0)                              \
      ACC = mfma16(AF, BF, ACC);                          \
    else                                                  \
      ACC = mfma16(BF, AF, ACC);                          \
  } while (0)
  const int t = threadIdx.x;
  for (int kt = 0; kt < KT_N; ++kt) {
    unsigned short* ab = LDS + (kt & 1) * 32768;
    unsigned short* bb = ab + 16384;
    const bool st = (kt + 2) < KT_N;
    const int ko2 = (kt + 2) * 64;
    bf16x8 af[4][2], bf0[2][2], bf1[2][2];

    // -- phase 0: reads A-lo + B01; MFMA lo x ni01
#pragma unroll
    for (int mi = 0; mi < 4; mi++) {
      const unsigned short* rp = ab + (rA0 + mi * 16) * 64;
      af[mi][0] = BC8(rp + ch0);
      af[mi][1] = BC8(rp + ch1);
    }
#pragma unroll
    for (int ni = 0; ni < 2; ni++) {
      const unsigned short* rp = bb + (rB0 + ni * 16) * 64;
      bf0[ni][0] = BC8(rp + ch0);
      bf0[ni][1] = BC8(rp + ch1);
    }
    __builtin_amdgcn_s_setprio(1);
#pragma unroll
    for (int mi = 0; mi < 4; mi++)
#pragma unroll
      for (int ni = 0; ni < 2; ni++) {
        MM(acc[mi][ni], af[mi][0], bf0[ni][0]);
        MM(acc[mi][ni], af[mi][1], bf0[ni][1]);
      }
    __builtin_amdgcn_s_setprio(0);
    asm volatile("s_waitcnt lgkmcnt(0)" ::: "memory");
    __builtin_amdgcn_s_barrier();
    __builtin_amdgcn_sched_barrier(0);

    // -- phase 1: stage A q0,q2 (read in p0); reads B23; MFMA lo x ni23
    if (st) {
      gload16(gA[0] + ko2, ab + 0 * 4096 + t * 8);
      gload16(gA[2] + ko2, ab + 2 * 4096 + t * 8);
    }
#pragma unroll
    for (int ni = 0; ni < 2; ni++) {
      const unsigned short* rp = bb + (rB0 + (2 + ni) * 16) * 64;
      bf1[ni][0] = BC8(rp + ch0);
      bf1[ni][1] = BC8(rp + ch1);
    }
    __builtin_amdgcn_s_setprio(1);
#pragma unroll
    for (int mi = 0; mi < 4; mi++)
#pragma unroll
      for (int ni = 0; ni < 2; ni++) {
        MM(acc[mi][2 + ni], af[mi][0], bf1[ni][0]);
        MM(acc[mi][2 + ni], af[mi][1], bf1[ni][1]);
      }
    __builtin_amdgcn_s_setprio(0);
    asm volatile("s_waitcnt lgkmcnt(0)" ::: "memory");
    __builtin_amdgcn_s_barrier();
    __builtin_amdgcn_sched_barrier(0);

    // -- phase 2: stage B all (read in p0/p1); reads A-hi; MFMA hi x ni23
    if (st) {
#pragma unroll
      for (int q = 0; q < 4; q++) gload16(gB[q] + ko2, bb + q * 4096 + t * 8);
    }
#pragma unroll
    for (int mi = 0; mi < 4; mi++) {
      const unsigned short* rp = ab + (rA0 + 64 + mi * 16) * 64;
      af[mi][0] = BC8(rp + ch0);
      af[mi][1] = BC8(rp + ch1);
    }
    __builtin_amdgcn_s_setprio(1);
#pragma unroll
    for (int mi = 0; mi < 4; mi++)
#pragma unroll
      for (int ni = 0; ni < 2; ni++) {
        MM(acc[4 + mi][2 + ni], af[mi][0], bf1[ni][0]);
        MM(acc[4 + mi][2 + ni], af[mi][1], bf1[ni][1]);
      }
    __builtin_amdgcn_s_setprio(0);
    asm volatile("s_waitcnt lgkmcnt(0)" ::: "memory");
    __builtin_amdgcn_s_barrier();
    __builtin_amdgcn_sched_barrier(0);

    // -- phase 3: stage A q1,q3 (read in p2); MFMA hi x ni01; counted vmcnt
    if (st) {
      gload16(gA[1] + ko2, ab + 1 * 4096 + t * 8);
      gload16(gA[3] + ko2, ab + 3 * 4096 + t * 8);
    }
    __builtin_amdgcn_s_setprio(1);
#pragma unroll
    for (int mi = 0; mi < 4; mi++)
#pragma unroll
      for (int ni = 0; ni < 2; ni++) {
        MM(acc[4 + mi][ni], af[mi][0], bf0[ni][0]);
        MM(acc[4 + mi][ni], af[mi][1], bf0[ni][1]);
      }
    __builtin_amdgcn_s_setprio(0);
    if (kt == KT_N - 2)
      asm volatile("s_waitcnt vmcnt(0)" ::: "memory");
    else
      asm volatile("s_waitcnt vmcnt(8)" ::: "memory");
    __builtin_amdgcn_s_barrier();
    __builtin_amdgcn_sched_barrier(0);
  }
#undef MM
}

// ---------------- fused Q/K/V projection (876 blocks) -----------------------
// ids 0..583: Q/K (m-major XCD remap); ids 584..875: V (C^T, coalesced-s
// epilogue). Fusion fills qk's 72-CU third-round tail with vt blocks and
// removes one launch bubble.
__global__ __launch_bounds__(512, 2) void gemm256u(
    const unsigned short* __restrict__ xb, const unsigned short* __restrict__ wb,
    const float* __restrict__ bq, const float* __restrict__ bk,
    const float* __restrict__ bv,
    unsigned short* __restrict__ qo, unsigned short* __restrict__ ko,
    unsigned short* __restrict__ vo) {
  __shared__ __align__(16) unsigned short LDS[65536];  // 128 KiB
  const int id = blockIdx.x;
  int m_tile, col, z;
  bool modeV;
  if (id < 584) {
    modeV = false;
    const int xcd = id & 7, j = id >> 3;
    const int p = xcd * 73 + j;       // bijective, 0..583
    m_tile = p >> 3;                  // 0..72
    col = p & 7;                      // 0..7 (col&3 -> n-block)
    z = col >> 2;                     // 0: Q, 1: K
  } else {
    modeV = true;
    const int q = id - 584;           // 0..291
    const int xcd = q & 7, j = q >> 3;
    const int p = (xcd < 4) ? xcd * 37 + j : 148 + (xcd - 4) * 36 + j;
    m_tile = p >> 2;                  // 0..72
    col = p & 3;                      // 0..3
    z = 2;
  }
  const int n0 = (modeV ? col : (col & 3)) * 256;
  const int m0 = m_tile * 256;

  const int t = threadIdx.x;        // 0..511
  const int lane = t & 63;
  const int w = t >> 6;             // 8 waves
  const int g = lane >> 4, c = lane & 15;
  const int wm = w & 1, wn = w >> 1;

  const unsigned short* W = wb + (size_t)z * (DM * DM);
  const float* bias = modeV ? bv : (z ? bk : bq);
  unsigned short* outp = modeV ? vo : (z ? ko : qo);

  const int srow = t >> 3;
  const int schunk = (t & 7) ^ (srow & 7);
  const unsigned short* gA[4];
#pragma unroll
  for (int q = 0; q < 4; q++) {
    int rg = m0 + q * 64 + srow;
    if (rg > MTOT - 1) rg = MTOT - 1;
    gA[q] = xb + (size_t)rg * DM + schunk * 8;
  }
  const unsigned short* gB[4];
#pragma unroll
  for (int q = 0; q < 4; q++)
    gB[q] = W + (size_t)(n0 + q * 64 + srow) * DM + schunk * 8;

  const int cx = c & 7;
  const int ch0 = (g ^ cx) * 8;        // kk=0 (k 0..31)
  const int ch1 = ((4 + g) ^ cx) * 8;  // kk=1 (k 32..63)

  f32x4 acc[8][4];
#pragma unroll
  for (int mi = 0; mi < 8; mi++)
#pragma unroll
    for (int ni = 0; ni < 4; ni++) acc[mi][ni] = (f32x4)0.0f;

  // prologue: stage K-tile 0 -> buf0, K-tile 1 -> buf1 (16 issues), wait 8
#pragma unroll
  for (int q = 0; q < 4; q++) gload16(gA[q], LDS + q * 4096 + t * 8);
#pragma unroll
  for (int q = 0; q < 4; q++) gload16(gB[q], LDS + 16384 + q * 4096 + t * 8);
#pragma unroll
  for (int q = 0; q < 4; q++) gload16(gA[q] + 64, LDS + 32768 + q * 4096 + t * 8);
#pragma unroll
  for (int q = 0; q < 4; q++)
    gload16(gB[q] + 64, LDS + 32768 + 16384 + q * 4096 + t * 8);
  asm volatile("s_waitcnt vmcnt(8)" ::: "memory");
  __builtin_amdgcn_s_barrier();
  __builtin_amdgcn_sched_barrier(0);

  const int rA0 = wm * 128 + c;
  const int rB0 = wn * 64 + c;

  if (!modeV)
    kloop256<0>(LDS, gA, gB, acc, rA0, rB0, ch0, ch1);
  else
    kloop256<1>(LDS, gA, gB, acc, rA0, rB0, ch0, ch1);

  if (!modeV) {
    float bias4[4];
#pragma unroll
    for (int ni = 0; ni < 4; ni++) bias4[ni] = bias[n0 + wn * 64 + ni * 16 + c];
#pragma unroll
    for (int mi = 0; mi < 8; mi++) {
      int mb = m0 + wm * 128 + mi * 16 + g * 4;
#pragma unroll
      for (int r = 0; r < 4; r++) {
        int m = mb + r;
        if (m >= MTOT) continue;
        int bi = m / SEQ;
        int s = m - bi * SEQ;
#pragma unroll
        for (int ni = 0; ni < 4; ni++) {
          int n = n0 + wn * 64 + ni * 16 + c;
          int hh = n >> 6, dd = n & 63;
          outp[(((size_t)bi * NH + hh) * SPAD + s) * HD + dd] =
              f2bf(acc[mi][ni][r] + bias4[ni]);
        }
      }
    }
  } else {
    // C^T: acc[mi][ni] elem (r, lane c): n = n0+wn*64+ni*16+g*4+r,
    // m = m0+wm*128+mi*16+c. Lanes c -> consecutive s (coalesced).
#pragma unroll
    for (int ni = 0; ni < 4; ni++) {
#pragma unroll
      for (int r = 0; r < 4; r++) {
        int n = n0 + wn * 64 + ni * 16 + g * 4 + r;
        int hh = n >> 6, dd = n & 63;
        float bn = bias[n];
#pragma unroll
        for (int mi = 0; mi < 8; mi++) {
          int m = m0 + wm * 128 + mi * 16 + c;
          if (m >= MTOT) continue;
          int bi = m / SEQ;
          int s = m - bi * SEQ;
          outp[(((size_t)bi * NH + hh) * HD + dd) * SPAD + s] =
              f2bf(acc[mi][ni][r] + bn);
        }
      }
    }
  }
}

// ---------------- flash attention v2 (R0: XCD-locality remap, kept) ---------
__global__ __launch_bounds__(256, 4) void attn_kernel(
    const unsigned short* __restrict__ Qb, const unsigned short* __restrict__ Kb,
    const unsigned short* __restrict__ Vt, float* __restrict__ out) {
  __shared__ __align__(16) unsigned short Ks[64 * 64];
  __shared__ __align__(16) unsigned short Vs[80 * 64];
  __shared__ __align__(16) unsigned short Pl[4][16 * 72];
  const int t = threadIdx.x, lane = t & 63, w = t >> 6;
  const int g = lane >> 4, c = lane & 15;

  const int id = blockIdx.x;          // 0..5119
  const int xcd = id & 7;
  const int slot = id >> 3;           // 0..639
  const int qt = slot % 10;
  const int pairIdx = slot / 10;      // 0..63
  const int pair = xcd * 64 + pairIdx;
  const int b = pair >> 4;
  const int h = pair & 15;

  const int q0 = qt * 64 + w * 16;
  const size_t bh = (size_t)b * NH + h;
  const unsigned short* Qp = Qb + bh * SPAD * HD;
  const unsigned short* Kp = Kb + bh * SPAD * HD;
  const unsigned short* Vp = Vt + bh * HD * SPAD;

  {
    int rr = t >> 4, col = (t & 15) * 4;
    unsigned short val = (rr == 0) ? (unsigned short)0x3F80 : (unsigned short)0;
    u16x4 v4 = {val, val, val, val};
    *(u16x4*)(Vs + (64 + rr) * 64 + col) = v4;
  }

  bf16x8 qf0 = __builtin_bit_cast(
      bf16x8, *(const u16x8*)(Qp + (size_t)(q0 + c) * HD + g * 8));
  bf16x8 qf1 = __builtin_bit_cast(
      bf16x8, *(const u16x8*)(Qp + (size_t)(q0 + c) * HD + 32 + g * 8));

  const int C0 = t, C1 = t + 256;
  const int r0 = C0 >> 3, cg0 = (C0 & 7) ^ (r0 & 7);
  const int r1 = C1 >> 3, cg1 = (C1 & 7) ^ (r1 & 7);
  const unsigned short* gK0 = Kp + (size_t)(r0 * 8 + cg0) * 8;
  const unsigned short* gK1 = Kp + (size_t)(r1 * 8 + cg1) * 8;
  const unsigned short* gV0 = Vp + (size_t)r0 * SPAD + cg0 * 8;
  const unsigned short* gV1 = Vp + (size_t)r1 * SPAD + cg1 * 8;
  unsigned short* lK0 = Ks + C0 * 8;
  unsigned short* lK1 = Ks + C1 * 8;
  unsigned short* lV0 = Vs + C0 * 8;
  unsigned short* lV1 = Vs + C1 * 8;

  f32x4 oacc[5];
#pragma unroll
  for (int nt = 0; nt < 5; nt++) oacc[nt] = (f32x4)0.0f;
  unsigned short* pl = &Pl[w][0];
  const float SC = 0.125f * 1.44269504f;

  for (int kt = 0; kt < 10; kt++) {
    const int kv0 = kt * 64;
    __syncthreads();
    gload16(gK0 + kv0 * 64, lK0);
    gload16(gK1 + kv0 * 64, lK1);
    gload16(gV0 + kv0, lV0);
    gload16(gV1 + kv0, lV1);
    __syncthreads();

    f32x4 sc[4];
#pragma unroll
    for (int nt = 0; nt < 4; nt++) {
      const int row = nt * 16 + c;
      const unsigned short* kb = Ks + row * 64;
      bf16x8 k0 = __builtin_bit_cast(
          bf16x8, *(const u16x8*)(kb + ((g ^ (row & 7)) * 8)));
      bf16x8 k1 = __builtin_bit_cast(
          bf16x8, *(const u16x8*)(kb + (((4 + g) ^ (row & 7)) * 8)));
      sc[nt] = mfma16(qf0, k0, (f32x4)0.0f);
      sc[nt] = mfma16(qf1, k1, sc[nt]);
    }

    if (kt == 9) {
#pragma unroll
      for (int nt = 0; nt < 4; nt++) {
        const bool valid = (kv0 + nt * 16 + c) < SEQ;
#pragma unroll
        for (int r = 0; r < 4; r++)
          sc[nt][r] = valid ? EXP2(sc[nt][r] * SC) : 0.0f;
      }
    } else {
#pragma unroll
      for (int nt = 0; nt < 4; nt++)
#pragma unroll
        for (int r = 0; r < 4; r++) sc[nt][r] = EXP2(sc[nt][r] * SC);
    }

#pragma unroll
    for (int nt = 0; nt < 4; nt++)
#pragma unroll
      for (int r = 0; r < 4; r++)
        pl[(g * 4 + r) * 72 + nt * 16 + c] = f2bf(sc[nt][r]);
    bf16x8 pa0 = __builtin_bit_cast(bf16x8, *(const u16x8*)(pl + c * 72 + g * 8));
    bf16x8 pa1 =
        __builtin_bit_cast(bf16x8, *(const u16x8*)(pl + c * 72 + 32 + g * 8));

#pragma unroll
    for (int nt = 0; nt < 5; nt++) {
      const int row = nt * 16 + c;
      const unsigned short* vb = Vs + row * 64;
      bf16x8 v0 = __builtin_bit_cast(
          bf16x8, *(const u16x8*)(vb + ((g ^ (row & 7)) * 8)));
      bf16x8 v1 = __builtin_bit_cast(
          bf16x8, *(const u16x8*)(vb + (((4 + g) ^ (row & 7)) * 8)));
      oacc[nt] = mfma16(pa0, v0, oacc[nt]);
      oacc[nt] = mfma16(pa1, v1, oacc[nt]);
    }
  }

#pragma unroll
  for (int r = 0; r < 4; r++) {
    int s = q0 + g * 4 + r;
    if (s >= SEQ) continue;
    float l = __shfl(oacc[4][r], lane & 48, 64);
    float inv = 1.0f / l;
#pragma unroll
    for (int nt = 0; nt < 4; nt++)
      out[((size_t)b * SEQ + s) * DM + h * HD + nt * 16 + c] =
          oacc[nt][r] * inv;
  }
}

extern "C" void kernel_launch(void* const* d_in, const int* in_sizes, int n_in,
                              void* d_out, int out_size, void* d_ws,
                              size_t ws_size, hipStream_t stream) {
  const float* x = (const float*)d_in[0];
  const float* Wq = (const float*)d_in[1];
  const float* bq = (const float*)d_in[2];
  const float* Wk = (const float*)d_in[3];
  const float* bk = (const float*)d_in[4];
  const float* Wv = (const float*)d_in[5];
  const float* bv = (const float*)d_in[6];
  float* out = (float*)d_out;

  const size_t nXB = (size_t)MTOT * DM;
  const size_t nWB = (size_t)3 * DM * DM;
  const size_t nQK = (size_t)NB * NH * SPAD * HD;
  const size_t needed = (nXB + nWB + 3 * nQK) * 2;
  if (ws_size < needed) return;

  unsigned short* xb = (unsigned short*)d_ws;
  unsigned short* wb = xb + nXB;
  unsigned short* Qb = wb + nWB;
  unsigned short* Kb = Qb + nQK;
  unsigned short* Vt = Kb + nQK;

  cvt_kernel<<<21536, 256, 0, stream>>>(x, Wq, Wk, Wv, xb, wb);
  gemm256u<<<876, 512, 0, stream>>>(xb, wb, bq, bk, bv, Qb, Kb, Vt);
  attn_kernel<<<5120, 256, 0, stream>>>(Qb, Kb, Vt, out);
}